// Round 10
// baseline (241.805 us; speedup 1.0000x reference)
//
#include <hip/hip_runtime.h>
#include <cstdint>
#include <cstddef>

typedef unsigned long long u64;
typedef unsigned int u32;

#define A_TOT   8400
#define NCLS    80
#define KSLOT   1024
#define NCHUNK  9
#define TOPK_N  1000
#define MAXDET  300
#define OUT_STRIDE (MAXDET * 6)

#define GLOBAL_AS const __attribute__((address_space(1))) void*
#define LDS_AS __attribute__((address_space(3))) void*

// ---------- helpers ----------

// stepwise f32 sigmoid with correctly-rounded f32 exp (via f64):
// e = fl32(exp(-x)); s = 1/(1+e)   -- replicates np-f32 semantics
__device__ __forceinline__ float sig32(float x) {
#pragma clang fp contract(off)
    float e = (float)exp(-(double)x);
    float t = 1.0f + e;
    return 1.0f / t;
}

__device__ __forceinline__ u32 key_hi_from_score(float s) {
    u32 u = __float_as_uint(s);
    return (u & 0x80000000u) ? ~u : (u | 0x80000000u);
}
__device__ __forceinline__ float score_from_key_hi(u32 t) {
    u32 u = (t & 0x80000000u) ? (t ^ 0x80000000u) : ~t;
    return __uint_as_float(u);
}

// merge-path: element of rank t (0-based) in the descending merge of two
// descending length-1024 lists A, B (t < 1024). Values across A and B are
// distinct wherever it matters (unique anchor index in low bits; zero-pads
// only ever meet strictly-positive real keys), so strict '>' is exact.
__device__ __forceinline__ u64 mp_rank(const u64* __restrict__ A,
                                       const u64* __restrict__ B, int t) {
    int lo = 0, hi = t;
    while (lo < hi) {                     // find max i with (i==0 || A[i-1] > B[t-i])
        int mid = (lo + hi + 1) >> 1;
        if (A[mid - 1] > B[t - mid]) lo = mid; else hi = mid - 1;
    }
    int i = lo, j = t - lo;               // i,j <= t < 1024: A[i], B[j] always valid
    u64 av = A[i], bv = B[j];
    return av > bv ? av : bv;
}

// ---------- 1. fused decode: global_load_lds staging, 1 anchor/thread ----------
__global__ __launch_bounds__(256) void k_decode(const float* __restrict__ preds,
                                                u64* __restrict__ key_raw,
                                                float4* __restrict__ dbox) {
#pragma clang fp contract(off)
    __shared__ float tile[2][16][256];
    int b = blockIdx.y;
    int a0 = blockIdx.x * 256;
    int t = threadIdx.x;
    int a = a0 + t;
    int nA = A_TOT - a0; if (nA > 256) nA = 256;
    int p4max = nA >> 2;                       // valid float4s per channel row
    const float* pb = preds + (size_t)b * 144 * A_TOT;

    int l  = t & 63;                           // lane
    int wv = t >> 6;                           // wave 0..3
    int lc = (l < p4max) ? l : (p4max - 1);    // tail-safe clamped lane pos

    auto stage = [&](int ch0, int buf) {
#pragma unroll
        for (int k = 0; k < 4; ++k) {
            int r = 4 * k + wv;                // wave-uniform row
            const float* gsrc = pb + (size_t)(ch0 + r) * A_TOT + a0 + 4 * lc;
            __builtin_amdgcn_global_load_lds((GLOBAL_AS)gsrc,
                                             (LDS_AS)&tile[buf][r][0],
                                             16, 0, 0);
        }
    };

    float d[4] = {0.f, 0.f, 0.f, 0.f};
    float m = -3.0e38f, m2 = -3.0e38f;
    int jm = 0;

    stage(0, 0);
    __syncthreads();                           // chunk 0 resident

    for (int cb = 0; cb < 9; ++cb) {
        int buf = cb & 1;
        if (cb + 1 < 9) stage((cb + 1) * 16, (cb + 1) & 1);   // overlap with compute
        if (t < nA) {
            float x[16];
#pragma unroll
            for (int r = 0; r < 16; ++r) x[r] = tile[buf][r][t];
            if (cb < 4) {
                // DFL softmax-expectation, exact reference op order
                float mx = x[0];
#pragma unroll
                for (int r = 1; r < 16; ++r) mx = fmaxf(mx, x[r]);
                float e[16], s = 0.f;
#pragma unroll
                for (int r = 0; r < 16; ++r) { e[r] = expf(x[r] - mx); s = s + e[r]; }
                float dd = 0.f;
#pragma unroll
                for (int r = 0; r < 16; ++r) { float pr = e[r] / s; dd = dd + pr * (float)r; }
                d[cb] = dd;
            } else {
                int cbase = (cb - 4) * 16;
#pragma unroll
                for (int r = 0; r < 16; ++r) {
                    int c = cbase + r;
                    float v = x[r];
                    if (v > m) { m2 = m; m = v; jm = c; }
                    else if (v > m2) { m2 = v; }
                }
            }
        }
        if (cb < 8) __syncthreads();           // drains vmcnt: next chunk resident
    }

    if (t >= nA) return;

    // ----- key (slow exact path rare: tie-gap < 1e-4 or saturated sigmoid) -----
    const float* pc = pb + (size_t)64 * A_TOT + a;
    float conf; int cls = jm;
    if ((m - m2) < 1e-4f || m > 7.0f) {
        float sb = -1.0f; int jb = 0;
        for (int c = 0; c < NCLS; ++c) {
            float s = sig32(pc[(size_t)c * A_TOT]);
            if (s > sb) { sb = s; jb = c; }
        }
        conf = sb; cls = jb;
    } else {
        conf = sig32(m);
    }
    float score = (conf > 0.25f) ? conf : -1.0f;
    u32 hi = key_hi_from_score(score);
    u32 lo = ((0x3FFFu - (u32)a) << 7) | (u32)cls;   // idx asc tie-break + cls
    key_raw[(size_t)b * A_TOT + a] = ((u64)hi << 32) | lo;

    // ----- box from d[0..3], exact reference op order -----
    int row, col; float stride;
    if (a < 6400)      { row = a / 80;          col = a % 80;          stride = 8.0f; }
    else if (a < 8000) { int aa = a - 6400; row = aa / 40; col = aa % 40; stride = 16.0f; }
    else               { int aa = a - 8000; row = aa / 20; col = aa % 20; stride = 32.0f; }
    float ax = (float)col + 0.5f;
    float ay = (float)row + 0.5f;
    float x1 = ax - d[0], y1 = ay - d[1];
    float x2 = ax + d[2], y2 = ay + d[3];
    float cx = (x1 + x2) / 2.0f, cy = (y1 + y2) / 2.0f;
    float w  = x2 - x1,          h  = y2 - y1;
    float4 db;
    db.x = cx * stride; db.y = cy * stride; db.z = w * stride; db.w = h * stride;
    dbox[(size_t)b * A_TOT + a] = db;
}

// ---------- 2a. bitonic sort of 1024-chunks (descending) ----------
__global__ __launch_bounds__(1024) void k_chunksort(const u64* __restrict__ key_raw,
                                                    u64* __restrict__ key_sorted) {
    __shared__ u64 s[KSLOT];
    int b = blockIdx.y, ch = blockIdx.x, t = threadIdx.x;
    int a = ch * KSLOT + t;
    s[t] = (a < A_TOT) ? key_raw[(size_t)b * A_TOT + a] : 0ull;
    __syncthreads();
    for (int k = 2; k <= KSLOT; k <<= 1) {
        for (int j = k >> 1; j > 0; j >>= 1) {
            int ixj = t ^ j;
            if (ixj > t) {
                u64 x = s[t], y = s[ixj];
                bool descBlock = ((t & k) == 0);
                bool sw = descBlock ? (x < y) : (x > y);
                if (sw) { s[t] = y; s[ixj] = x; }
            }
            __syncthreads();
        }
    }
    key_sorted[((size_t)b * NCHUNK + ch) * KSLOT + t] = s[t];
}

// ---------- 3. fused NMS: select + prep + matrix + scan + final ----------
// One block per batch (1024 thr, 152KB LDS). masks matrix lives in LDS
// (union'd with the select phase's merge buffer), scan reads resident rows,
// final writes straight from the thread's own registers (thread t == slot t).
struct SNms {
    union {
        u64 masks[KSLOT][16];   // 128KB, matrix/scan phases
        u64 L[5 * KSLOT];       // 40KB, select phase scratch
    } u;
    float4 sob[KSLOT];          // 16KB offset boxes
    float  sar[KSLOT];          // 4KB areas
    u32    sval[KSLOT];         // 4KB valid flags
    u64    keepw[16];
    int    pref[16];
};

__global__ __launch_bounds__(1024) void k_nms(const u64* __restrict__ key_sorted,
                                              const float4* __restrict__ dbox,
                                              float* __restrict__ out) {
#pragma clang fp contract(off)
    __shared__ SNms sm;
    int b = blockIdx.x, t = threadIdx.x;
    const u64* KS = key_sorted + (size_t)b * NCHUNK * KSLOT;
    u64* Lp = sm.u.L;

    // ---- select: merge-path tree top-1024 (math identical to k_select) ----
    u64 r0 = mp_rank(KS + 0 * KSLOT, KS + 1 * KSLOT, t);
    u64 r1 = mp_rank(KS + 2 * KSLOT, KS + 3 * KSLOT, t);
    u64 r2 = mp_rank(KS + 4 * KSLOT, KS + 5 * KSLOT, t);
    u64 r3 = mp_rank(KS + 6 * KSLOT, KS + 7 * KSLOT, t);
    u64 r4 = KS[8 * KSLOT + t];
    Lp[0 * KSLOT + t] = r0; Lp[1 * KSLOT + t] = r1;
    Lp[2 * KSLOT + t] = r2; Lp[3 * KSLOT + t] = r3;
    Lp[4 * KSLOT + t] = r4;
    __syncthreads();
    u64 m0 = mp_rank(Lp + 0 * KSLOT, Lp + 1 * KSLOT, t);
    u64 m1 = mp_rank(Lp + 2 * KSLOT, Lp + 3 * KSLOT, t);
    __syncthreads();
    Lp[0 * KSLOT + t] = m0; Lp[1 * KSLOT + t] = m1;
    __syncthreads();
    u64 s0 = mp_rank(Lp + 0 * KSLOT, Lp + 1 * KSLOT, t);
    __syncthreads();
    Lp[0 * KSLOT + t] = s0;
    __syncthreads();
    u64 key = mp_rank(Lp + 0 * KSLOT, Lp + 4 * KSLOT, t);

    // ---- prep into LDS + registers (math identical to k_prep) ----
    u32 hi = (u32)(key >> 32);
    u32 lo = (u32)key;
    bool valid = (t < TOPK_N) && (hi & 0x80000000u);
    float bx1 = 0.f, by1 = 0.f, bx2 = 0.f, by2 = 0.f;
    if (!valid) {
        sm.sob[t] = make_float4(0.f, 0.f, 0.f, 0.f);
        sm.sar[t] = 0.f; sm.sval[t] = 0u;
    } else {
        int a   = 0x3FFF - (int)((lo >> 7) & 0x3FFFu);
        int cls = (int)(lo & 0x7Fu);
        float4 db = dbox[(size_t)b * A_TOT + a];
        bx1 = db.x - db.z / 2.0f; by1 = db.y - db.w / 2.0f;
        bx2 = db.x + db.z / 2.0f; by2 = db.y + db.w / 2.0f;
        float off = (float)cls * 7680.0f;
        float o0 = bx1 + off, o1 = by1 + off, o2 = bx2 + off, o3 = by2 + off;
        sm.sob[t] = make_float4(o0, o1, o2, o3);
        sm.sar[t] = (o2 - o0) * (o3 - o1);
        sm.sval[t] = 1u;
    }
    __syncthreads();                          // L dead; sob/sar/sval ready

    // ---- zero masks (aliases L, now dead) ----
    for (int z = t; z < KSLOT * 16; z += 1024) ((u64*)sm.u.masks)[z] = 0ull;
    __syncthreads();

    // ---- matrix: 136 (rblk,w>=rblk) pairs spread over 16 waves ----
    {
        int lane = t & 63, wv = t >> 6;
        for (int p = wv; p < 136; p += 16) {
            int rblk = 0, acc = 0;
            while (acc + (16 - rblk) <= p) { acc += 16 - rblk; ++rblk; }
            int w = rblk + (p - acc);
            int i = rblk * 64 + lane;
            float4 bi = sm.sob[i];
            float Ai = sm.sar[i];
            u64 mword = 0ull;
            for (int bit = 0; bit < 64; ++bit) {
                int j = (w << 6) + bit;
                float4 bj = sm.sob[j];        // wave-uniform -> LDS broadcast
                float Aj = sm.sar[j];
                float lt0 = fmaxf(bi.x, bj.x);
                float lt1 = fmaxf(bi.y, bj.y);
                float rb0 = fminf(bi.z, bj.z);
                float rb1 = fminf(bi.w, bj.w);
                float ww = fmaxf(rb0 - lt0, 0.0f);
                float hh = fmaxf(rb1 - lt1, 0.0f);
                float inter = ww * hh;
                float den = ((Ai + Aj) - inter) + 1e-7f;
                float iou = inter / den;
                if ((j > i) && (iou > 0.45f)) mword |= (1ull << bit);
            }
            sm.u.masks[i][w ^ (i & 7)] = mword;   // swizzled store (8-way, not 64-way)
        }
    }
    __syncthreads();

    // ---- scan: wave 0, greedy live-mask skip, early stop (logic identical) ----
    if (t < 64) {
        int lane = t;
        u64 kw = 0ull, rem = 0ull;
        int kept = 0;
        for (int cw = 0; cw < 16; ++cw) {
            u32 vf = sm.sval[cw * 64 + lane];
            u64 valid_w = __ballot(vf != 0u);
            u64 live = valid_w & ~__shfl(rem, cw);
            while (live) {
                int i = __ffsll(live) - 1;        // lowest live slot: always kept
                if (lane == cw) kw |= (1ull << i);
                int rowi = cw * 64 + i;
                u64 mm = (lane < 16) ? sm.u.masks[rowi][lane ^ (rowi & 7)] : 0ull;
                rem |= mm;
                ++kept;
                if (kept >= MAXDET) break;
                live &= ~(__shfl(mm, cw) | (1ull << i));
            }
            if (kept >= MAXDET) break;
        }
        if (lane < 16) sm.keepw[lane] = kw;
    }
    __syncthreads();

    // ---- final: compact kept (ordered) into first 300 rows ----
    float* outb = out + (size_t)b * OUT_STRIDE;
    for (int z = t; z < OUT_STRIDE; z += 1024) outb[z] = 0.0f;
    if (t == 0) {
        int s2 = 0;
        for (int w2 = 0; w2 < 16; ++w2) { sm.pref[w2] = s2; s2 += __popcll(sm.keepw[w2]); }
    }
    __syncthreads();
    int w3 = t >> 6, bit3 = t & 63;
    if ((sm.keepw[w3] >> bit3) & 1ull) {
        u64 below = (bit3 == 0) ? 0ull : (sm.keepw[w3] & ((1ull << bit3) - 1ull));
        int rank = sm.pref[w3] + __popcll(below);
        if (rank < MAXDET) {
            float score = score_from_key_hi(hi);
            float clsf = (float)(lo & 0x7Fu);
            float* o = outb + rank * 6;
            o[0] = bx1; o[1] = by1; o[2] = bx2; o[3] = by2;
            o[4] = score; o[5] = clsf;
        }
    }
}

// ---------- launch ----------
extern "C" void kernel_launch(void* const* d_in, const int* in_sizes, int n_in,
                              void* d_out, int out_size, void* d_ws, size_t ws_size,
                              hipStream_t stream) {
    const float* preds = (const float*)d_in[0];
    float* out = (float*)d_out;
    int B = in_sizes[0] / (144 * A_TOT);

    char* ws = (char*)d_ws;
    size_t off = 0;
    u64* key_raw    = (u64*)(ws + off); off += (size_t)B * A_TOT * 8;
    u64* key_sorted = (u64*)(ws + off); off += (size_t)B * NCHUNK * KSLOT * 8;
    float4* dbox    = (float4*)(ws + off); off += (size_t)B * A_TOT * 16;

    k_decode<<<dim3((A_TOT + 255) / 256, B), 256, 0, stream>>>(preds, key_raw, dbox);
    k_chunksort<<<dim3(NCHUNK, B), KSLOT, 0, stream>>>(key_raw, key_sorted);
    k_nms<<<B, KSLOT, 0, stream>>>(key_sorted, dbox, out);
}

// Round 11
// 181.809 us; speedup vs baseline: 1.3300x; 1.3300x over previous
//
#include <hip/hip_runtime.h>
#include <cstdint>
#include <cstddef>

typedef unsigned long long u64;
typedef unsigned int u32;

#define A_TOT   8400
#define NCLS    80
#define KSLOT   1024
#define NCHUNK  9
#define TOPK_N  1000
#define MAXDET  300
#define OUT_STRIDE (MAXDET * 6)

#define GLOBAL_AS const __attribute__((address_space(1))) void*
#define LDS_AS __attribute__((address_space(3))) void*

// ---------- helpers ----------

// stepwise f32 sigmoid with correctly-rounded f32 exp (via f64):
// e = fl32(exp(-x)); s = 1/(1+e)   -- replicates np-f32 semantics
__device__ __forceinline__ float sig32(float x) {
#pragma clang fp contract(off)
    float e = (float)exp(-(double)x);
    float t = 1.0f + e;
    return 1.0f / t;
}

__device__ __forceinline__ u32 key_hi_from_score(float s) {
    u32 u = __float_as_uint(s);
    return (u & 0x80000000u) ? ~u : (u | 0x80000000u);
}
__device__ __forceinline__ float score_from_key_hi(u32 t) {
    u32 u = (t & 0x80000000u) ? (t ^ 0x80000000u) : ~t;
    return __uint_as_float(u);
}

// merge-path: element of rank t (0-based) in the descending merge of two
// descending length-1024 lists A, B (t < 1024). Values across A and B are
// distinct wherever it matters (unique anchor index in low bits; zero-pads
// only ever meet strictly-positive real keys), so strict '>' is exact.
__device__ __forceinline__ u64 mp_rank(const u64* A, const u64* B, int t) {
    int lo = 0, hi = t;
    while (lo < hi) {                     // find max i with (i==0 || A[i-1] > B[t-i])
        int mid = (lo + hi + 1) >> 1;
        if (A[mid - 1] > B[t - mid]) lo = mid; else hi = mid - 1;
    }
    int i = lo, j = t - lo;               // i,j <= t < 1024: A[i], B[j] always valid
    u64 av = A[i], bv = B[j];
    return av > bv ? av : bv;
}

// ---------- 1. fused decode: global_load_lds staging, 1 anchor/thread ----------
__global__ __launch_bounds__(256) void k_decode(const float* __restrict__ preds,
                                                u64* __restrict__ key_raw,
                                                float4* __restrict__ dbox) {
#pragma clang fp contract(off)
    __shared__ float tile[2][16][256];
    int b = blockIdx.y;
    int a0 = blockIdx.x * 256;
    int t = threadIdx.x;
    int a = a0 + t;
    int nA = A_TOT - a0; if (nA > 256) nA = 256;
    int p4max = nA >> 2;                       // valid float4s per channel row
    const float* pb = preds + (size_t)b * 144 * A_TOT;

    int l  = t & 63;                           // lane
    int wv = t >> 6;                           // wave 0..3
    int lc = (l < p4max) ? l : (p4max - 1);    // tail-safe clamped lane pos

    auto stage = [&](int ch0, int buf) {
#pragma unroll
        for (int k = 0; k < 4; ++k) {
            int r = 4 * k + wv;                // wave-uniform row
            const float* gsrc = pb + (size_t)(ch0 + r) * A_TOT + a0 + 4 * lc;
            __builtin_amdgcn_global_load_lds((GLOBAL_AS)gsrc,
                                             (LDS_AS)&tile[buf][r][0],
                                             16, 0, 0);
        }
    };

    float d[4] = {0.f, 0.f, 0.f, 0.f};
    float m = -3.0e38f, m2 = -3.0e38f;
    int jm = 0;

    stage(0, 0);
    __syncthreads();                           // chunk 0 resident

    for (int cb = 0; cb < 9; ++cb) {
        int buf = cb & 1;
        if (cb + 1 < 9) stage((cb + 1) * 16, (cb + 1) & 1);   // overlap with compute
        if (t < nA) {
            float x[16];
#pragma unroll
            for (int r = 0; r < 16; ++r) x[r] = tile[buf][r][t];
            if (cb < 4) {
                // DFL softmax-expectation, exact reference op order
                float mx = x[0];
#pragma unroll
                for (int r = 1; r < 16; ++r) mx = fmaxf(mx, x[r]);
                float e[16], s = 0.f;
#pragma unroll
                for (int r = 0; r < 16; ++r) { e[r] = expf(x[r] - mx); s = s + e[r]; }
                float dd = 0.f;
#pragma unroll
                for (int r = 0; r < 16; ++r) { float pr = e[r] / s; dd = dd + pr * (float)r; }
                d[cb] = dd;
            } else {
                int cbase = (cb - 4) * 16;
#pragma unroll
                for (int r = 0; r < 16; ++r) {
                    int c = cbase + r;
                    float v = x[r];
                    if (v > m) { m2 = m; m = v; jm = c; }
                    else if (v > m2) { m2 = v; }
                }
            }
        }
        if (cb < 8) __syncthreads();           // drains vmcnt: next chunk resident
    }

    if (t >= nA) return;

    // ----- key (slow exact path rare: tie-gap < 1e-4 or saturated sigmoid) -----
    const float* pc = pb + (size_t)64 * A_TOT + a;
    float conf; int cls = jm;
    if ((m - m2) < 1e-4f || m > 7.0f) {
        float sb = -1.0f; int jb = 0;
        for (int c = 0; c < NCLS; ++c) {
            float s = sig32(pc[(size_t)c * A_TOT]);
            if (s > sb) { sb = s; jb = c; }
        }
        conf = sb; cls = jb;
    } else {
        conf = sig32(m);
    }
    float score = (conf > 0.25f) ? conf : -1.0f;
    u32 hi = key_hi_from_score(score);
    u32 lo = ((0x3FFFu - (u32)a) << 7) | (u32)cls;   // idx asc tie-break + cls
    key_raw[(size_t)b * A_TOT + a] = ((u64)hi << 32) | lo;

    // ----- box from d[0..3], exact reference op order -----
    int row, col; float stride;
    if (a < 6400)      { row = a / 80;          col = a % 80;          stride = 8.0f; }
    else if (a < 8000) { int aa = a - 6400; row = aa / 40; col = aa % 40; stride = 16.0f; }
    else               { int aa = a - 8000; row = aa / 20; col = aa % 20; stride = 32.0f; }
    float ax = (float)col + 0.5f;
    float ay = (float)row + 0.5f;
    float x1 = ax - d[0], y1 = ay - d[1];
    float x2 = ax + d[2], y2 = ay + d[3];
    float cx = (x1 + x2) / 2.0f, cy = (y1 + y2) / 2.0f;
    float w  = x2 - x1,          h  = y2 - y1;
    float4 db;
    db.x = cx * stride; db.y = cy * stride; db.z = w * stride; db.w = h * stride;
    dbox[(size_t)b * A_TOT + a] = db;
}

// ---------- 2a. bitonic sort of 1024-chunks (descending) ----------
__global__ __launch_bounds__(1024) void k_chunksort(const u64* __restrict__ key_raw,
                                                    u64* __restrict__ key_sorted) {
    __shared__ u64 s[KSLOT];
    int b = blockIdx.y, ch = blockIdx.x, t = threadIdx.x;
    int a = ch * KSLOT + t;
    s[t] = (a < A_TOT) ? key_raw[(size_t)b * A_TOT + a] : 0ull;
    __syncthreads();
    for (int k = 2; k <= KSLOT; k <<= 1) {
        for (int j = k >> 1; j > 0; j >>= 1) {
            int ixj = t ^ j;
            if (ixj > t) {
                u64 x = s[t], y = s[ixj];
                bool descBlock = ((t & k) == 0);
                bool sw = descBlock ? (x < y) : (x > y);
                if (sw) { s[t] = y; s[ixj] = x; }
            }
            __syncthreads();
        }
    }
    key_sorted[((size_t)b * NCHUNK + ch) * KSLOT + t] = s[t];
}

// ---------- 2b+3. select: LDS-staged merge-path top-1024 + inline prep ----------
// All 9 chunks staged to LDS with coalesced loads first; the per-thread
// divergent binary searches then run at LDS latency instead of L2/HBM.
__global__ __launch_bounds__(1024) void k_select(const u64* __restrict__ key_sorted,
                                                 u64* __restrict__ topk,
                                                 const float4* __restrict__ dbox,
                                                 float* __restrict__ tb,
                                                 float* __restrict__ ob,
                                                 float* __restrict__ area,
                                                 u32* __restrict__ validf) {
#pragma clang fp contract(off)
    __shared__ u64 CH[NCHUNK * KSLOT];           // 72 KB
    int b = blockIdx.x, t = threadIdx.x;
    const u64* KS = key_sorted + (size_t)b * NCHUNK * KSLOT;
    for (int idx = t; idx < NCHUNK * KSLOT; idx += 1024) CH[idx] = KS[idx];
    __syncthreads();

    // Level 1: (0,1) (2,3) (4,5) (6,7); chunk 8 carried
    u64 r0 = mp_rank(CH + 0 * KSLOT, CH + 1 * KSLOT, t);
    u64 r1 = mp_rank(CH + 2 * KSLOT, CH + 3 * KSLOT, t);
    u64 r2 = mp_rank(CH + 4 * KSLOT, CH + 5 * KSLOT, t);
    u64 r3 = mp_rank(CH + 6 * KSLOT, CH + 7 * KSLOT, t);
    u64 r4 = CH[8 * KSLOT + t];
    __syncthreads();
    CH[0 * KSLOT + t] = r0; CH[1 * KSLOT + t] = r1;
    CH[2 * KSLOT + t] = r2; CH[3 * KSLOT + t] = r3;
    CH[4 * KSLOT + t] = r4;
    __syncthreads();

    // Level 2
    u64 m0 = mp_rank(CH + 0 * KSLOT, CH + 1 * KSLOT, t);
    u64 m1 = mp_rank(CH + 2 * KSLOT, CH + 3 * KSLOT, t);
    __syncthreads();
    CH[0 * KSLOT + t] = m0; CH[1 * KSLOT + t] = m1;
    __syncthreads();

    // Level 3
    u64 s0 = mp_rank(CH + 0 * KSLOT, CH + 1 * KSLOT, t);
    __syncthreads();
    CH[0 * KSLOT + t] = s0;
    __syncthreads();

    // Level 4: (merged 0-7, chunk 8)
    u64 key = mp_rank(CH + 0 * KSLOT, CH + 4 * KSLOT, t);
    size_t si = (size_t)b * KSLOT + t;
    topk[si] = key;

    // ----- inline prep (textually identical math) -----
    u32 hi = (u32)(key >> 32);
    u32 lo = (u32)key;
    bool valid = (t < TOPK_N) && (hi & 0x80000000u);
    if (!valid) {
        tb[si*4+0]=0.f; tb[si*4+1]=0.f; tb[si*4+2]=0.f; tb[si*4+3]=0.f;
        ob[si*4+0]=0.f; ob[si*4+1]=0.f; ob[si*4+2]=0.f; ob[si*4+3]=0.f;
        area[si] = 0.f; validf[si] = 0u;
        return;
    }
    int a   = 0x3FFF - (int)((lo >> 7) & 0x3FFFu);
    int cls = (int)(lo & 0x7Fu);

    float4 db = dbox[(size_t)b * A_TOT + a];
    float bx1 = db.x - db.z / 2.0f, by1 = db.y - db.w / 2.0f;
    float bx2 = db.x + db.z / 2.0f, by2 = db.y + db.w / 2.0f;
    tb[si*4+0] = bx1; tb[si*4+1] = by1; tb[si*4+2] = bx2; tb[si*4+3] = by2;

    float off = (float)cls * 7680.0f;
    float o0 = bx1 + off, o1 = by1 + off, o2 = bx2 + off, o3 = by2 + off;
    ob[si*4+0] = o0; ob[si*4+1] = o1; ob[si*4+2] = o2; ob[si*4+3] = o3;
    area[si] = (o2 - o0) * (o3 - o1);
    validf[si] = 1u;
}

// ---------- 4. suppression bitmask matrix (512 blocks, LDS broadcast) ----------
__global__ __launch_bounds__(256) void k_matrix(const float* __restrict__ ob,
                                                const float* __restrict__ area,
                                                u64* __restrict__ masks) {
#pragma clang fp contract(off)
    __shared__ float4 sob[KSLOT];
    __shared__ float  sar[KSLOT];
    int b = blockIdx.y, rblk = blockIdx.x, tid = threadIdx.x;
    const float4* gob = (const float4*)(ob + (size_t)b * KSLOT * 4);
    const float*  gar = area + (size_t)b * KSLOT;
    for (int i = tid; i < KSLOT; i += blockDim.x) { sob[i] = gob[i]; sar[i] = gar[i]; }
    __syncthreads();

    int lane = tid & 63;
    int wave = tid >> 6;               // 0..3
    int i = rblk * 64 + lane;
    float4 bi = sob[i];
    float Ai = sar[i];

#pragma unroll
    for (int wl = 0; wl < 4; ++wl) {
        int w = wave * 4 + wl;         // wave-uniform word index 0..15
        u64 mword = 0ull;
        if (w >= rblk) {               // whole word below diagonal -> all zero
            for (int bit = 0; bit < 64; ++bit) {
                int j = (w << 6) + bit;
                float4 bj = sob[j];    // broadcast (uniform addr across wave)
                float Aj = sar[j];     // broadcast
                float lt0 = fmaxf(bi.x, bj.x);
                float lt1 = fmaxf(bi.y, bj.y);
                float rb0 = fminf(bi.z, bj.z);
                float rb1 = fminf(bi.w, bj.w);
                float ww = fmaxf(rb0 - lt0, 0.0f);
                float hh = fmaxf(rb1 - lt1, 0.0f);
                float inter = ww * hh;
                float den = ((Ai + Aj) - inter) + 1e-7f;
                float iou = inter / den;
                if ((j > i) && (iou > 0.45f)) mword |= (1ull << bit);
            }
        }
        masks[((size_t)b * KSLOT + i) * 16 + w] = mword;
    }
}

// ---------- 5. greedy scan (speculative prefetch) + fused finalize ----------
// Per-kept chain shortened by speculatively loading the row of the NEXT live
// candidate (second-lowest live bit) in parallel with the current row's use;
// the guess is verified against the true ffs(live), so greedy semantics are
// exact. Consecutive top candidates are usually different classes -> high hit
// rate -> the ds_read latency hides.
__global__ __launch_bounds__(64) void k_scan(const u64* __restrict__ masks,
                                             const u32* __restrict__ validf,
                                             const u64* __restrict__ topk,
                                             const float* __restrict__ tb,
                                             float* __restrict__ out) {
    __shared__ u64 rows[KSLOT];          // 8KB: current word's 64 rows x 16 words
    __shared__ u64 keepw[16];
    __shared__ int pref[16];
    int b = blockIdx.x, lane = threadIdx.x;
    const char* base = (const char*)(masks + (size_t)b * KSLOT * 16);

    // prefetch word 0's 8KB block into registers (coalesced dwordx4)
    float4 r0, r1, r2, r3, r4, r5, r6, r7;
    {
        const float4* src = (const float4*)base;
        r0 = src[0*64 + lane]; r1 = src[1*64 + lane];
        r2 = src[2*64 + lane]; r3 = src[3*64 + lane];
        r4 = src[4*64 + lane]; r5 = src[5*64 + lane];
        r6 = src[6*64 + lane]; r7 = src[7*64 + lane];
    }

    u64 kw = 0ull;       // lane l<16 owns keep word l
    u64 rem = 0ull;      // lane l<16 owns removed word l
    int kept = 0;

    for (int cw = 0; cw < 16; ++cw) {
        {
            float4* dst = (float4*)rows;
            dst[0*64 + lane] = r0; dst[1*64 + lane] = r1;
            dst[2*64 + lane] = r2; dst[3*64 + lane] = r3;
            dst[4*64 + lane] = r4; dst[5*64 + lane] = r5;
            dst[6*64 + lane] = r6; dst[7*64 + lane] = r7;
        }
        u32 vf = validf[(size_t)b * KSLOT + cw * 64 + lane];
        u64 valid_w = __ballot(vf != 0u);
        __syncthreads();
        // issue next word's loads (overlap with the serial scan below)
        if (cw < 15) {
            const float4* src = (const float4*)(base + (size_t)(cw + 1) * 8192);
            r0 = src[0*64 + lane]; r1 = src[1*64 + lane];
            r2 = src[2*64 + lane]; r3 = src[3*64 + lane];
            r4 = src[4*64 + lane]; r5 = src[5*64 + lane];
            r6 = src[6*64 + lane]; r7 = src[7*64 + lane];
        }

        u64 live = valid_w & ~__shfl(rem, cw);
        if (live) {
            int i = __ffsll(live) - 1;               // lowest live: always kept
            u64 m = (lane < 16) ? rows[i * 16 + lane] : 0ull;
            for (;;) {
                if (lane == cw) kw |= (1ull << i);
                rem |= m;
                ++kept;
                if (kept >= MAXDET) break;           // only first 300 emitted
                u64 live_wo = live & ~(1ull << i);
                int g = -1; u64 mg = 0ull;
                if (live_wo) {                        // speculative next-row load
                    g = __ffsll(live_wo) - 1;
                    mg = (lane < 16) ? rows[g * 16 + lane] : 0ull;
                }
                live = live_wo & ~__shfl(m, cw);
                if (!live) break;
                i = __ffsll(live) - 1;
                m = (i == g) ? mg : ((lane < 16) ? rows[i * 16 + lane] : 0ull);
            }
        }
        if (kept >= MAXDET) break;
        __syncthreads();   // all lanes done reading rows before next overwrite
    }

    // ---- fused finalize: compact kept (ordered) into first 300 rows ----
    if (lane < 16) keepw[lane] = kw;
    __syncthreads();
    if (lane == 0) {
        int s = 0;
        for (int w = 0; w < 16; ++w) { pref[w] = s; s += __popcll(keepw[w]); }
    }
    __syncthreads();
    float* outb = out + (size_t)b * OUT_STRIDE;
    for (int z = lane; z < OUT_STRIDE; z += 64) outb[z] = 0.0f;
    __syncthreads();
    for (int w2 = 0; w2 < 16; ++w2) {
        u64 kwv = keepw[w2];
        if ((kwv >> lane) & 1ull) {
            u64 below = (lane == 0) ? 0ull : (kwv & ((1ull << lane) - 1ull));
            int rank = pref[w2] + __popcll(below);
            if (rank < MAXDET) {
                size_t si = (size_t)b * KSLOT + w2 * 64 + lane;
                u64 key = topk[si];
                u32 hi = (u32)(key >> 32);
                u32 lo = (u32)key;
                float score = score_from_key_hi(hi);
                float clsf = (float)(lo & 0x7Fu);
                float* o = outb + rank * 6;
                o[0] = tb[si*4+0]; o[1] = tb[si*4+1];
                o[2] = tb[si*4+2]; o[3] = tb[si*4+3];
                o[4] = score; o[5] = clsf;
            }
        }
    }
}

// ---------- launch ----------
extern "C" void kernel_launch(void* const* d_in, const int* in_sizes, int n_in,
                              void* d_out, int out_size, void* d_ws, size_t ws_size,
                              hipStream_t stream) {
    const float* preds = (const float*)d_in[0];
    float* out = (float*)d_out;
    int B = in_sizes[0] / (144 * A_TOT);

    char* ws = (char*)d_ws;
    size_t off = 0;
    u64* key_raw    = (u64*)(ws + off); off += (size_t)B * A_TOT * 8;
    u64* key_sorted = (u64*)(ws + off); off += (size_t)B * NCHUNK * KSLOT * 8;
    u64* topk       = (u64*)(ws + off); off += (size_t)B * KSLOT * 8;
    float4* dbox    = (float4*)(ws + off); off += (size_t)B * A_TOT * 16;
    float* tb       = (float*)(ws + off); off += (size_t)B * KSLOT * 4 * 4;
    float* obuf     = (float*)(ws + off); off += (size_t)B * KSLOT * 4 * 4;
    float* area     = (float*)(ws + off); off += (size_t)B * KSLOT * 4;
    u32* validf     = (u32*)(ws + off); off += (size_t)B * KSLOT * 4;
    u64* masks      = (u64*)(ws + off); off += (size_t)B * KSLOT * 16 * 8;

    k_decode<<<dim3((A_TOT + 255) / 256, B), 256, 0, stream>>>(preds, key_raw, dbox);
    k_chunksort<<<dim3(NCHUNK, B), KSLOT, 0, stream>>>(key_raw, key_sorted);
    k_select<<<B, KSLOT, 0, stream>>>(key_sorted, topk, dbox, tb, obuf, area, validf);
    k_matrix<<<dim3(16, B), 256, 0, stream>>>(obuf, area, masks);
    k_scan<<<B, 64, 0, stream>>>(masks, validf, topk, tb, out);
}

// Round 13
// 176.981 us; speedup vs baseline: 1.3663x; 1.0273x over previous
//
#include <hip/hip_runtime.h>
#include <cstdint>
#include <cstddef>

typedef unsigned long long u64;
typedef unsigned int u32;

#define A_TOT   8400
#define NCLS    80
#define KSLOT   1024
#define NCHUNK  9
#define TOPK_N  1000
#define MAXDET  300
#define OUT_STRIDE (MAXDET * 6)

#define GLOBAL_AS const __attribute__((address_space(1))) void*
#define LDS_AS __attribute__((address_space(3))) void*

// ---------- helpers ----------

// stepwise f32 sigmoid with correctly-rounded f32 exp (via f64):
// e = fl32(exp(-x)); s = 1/(1+e)   -- replicates np-f32 semantics
__device__ __forceinline__ float sig32(float x) {
#pragma clang fp contract(off)
    float e = (float)exp(-(double)x);
    float t = 1.0f + e;
    return 1.0f / t;
}

__device__ __forceinline__ u32 key_hi_from_score(float s) {
    u32 u = __float_as_uint(s);
    return (u & 0x80000000u) ? ~u : (u | 0x80000000u);
}
__device__ __forceinline__ float score_from_key_hi(u32 t) {
    u32 u = (t & 0x80000000u) ? (t ^ 0x80000000u) : ~t;
    return __uint_as_float(u);
}

// merge-path: element of rank t (0-based) in the descending merge of two
// descending length-1024 lists A, B (t < 1024). Values across A and B are
// distinct wherever it matters (unique anchor index in low bits; zero-pads
// only ever meet strictly-positive real keys), so strict '>' is exact.
__device__ __forceinline__ u64 mp_rank(const u64* A, const u64* B, int t) {
    int lo = 0, hi = t;
    while (lo < hi) {                     // find max i with (i==0 || A[i-1] > B[t-i])
        int mid = (lo + hi + 1) >> 1;
        if (A[mid - 1] > B[t - mid]) lo = mid; else hi = mid - 1;
    }
    int i = lo, j = t - lo;               // i,j <= t < 1024: A[i], B[j] always valid
    u64 av = A[i], bv = B[j];
    return av > bv ? av : bv;
}

// ---------- 1. fused decode: global_load_lds staging, 1 anchor/thread ----------
__global__ __launch_bounds__(256) void k_decode(const float* __restrict__ preds,
                                                u64* __restrict__ key_raw,
                                                float4* __restrict__ dbox) {
#pragma clang fp contract(off)
    __shared__ float tile[2][16][256];
    int b = blockIdx.y;
    int a0 = blockIdx.x * 256;
    int t = threadIdx.x;
    int a = a0 + t;
    int nA = A_TOT - a0; if (nA > 256) nA = 256;
    int p4max = nA >> 2;                       // valid float4s per channel row
    const float* pb = preds + (size_t)b * 144 * A_TOT;

    int l  = t & 63;                           // lane
    int wv = t >> 6;                           // wave 0..3
    int lc = (l < p4max) ? l : (p4max - 1);    // tail-safe clamped lane pos

    auto stage = [&](int ch0, int buf) {
#pragma unroll
        for (int k = 0; k < 4; ++k) {
            int r = 4 * k + wv;                // wave-uniform row
            const float* gsrc = pb + (size_t)(ch0 + r) * A_TOT + a0 + 4 * lc;
            __builtin_amdgcn_global_load_lds((GLOBAL_AS)gsrc,
                                             (LDS_AS)&tile[buf][r][0],
                                             16, 0, 0);
        }
    };

    float d[4] = {0.f, 0.f, 0.f, 0.f};
    float m = -3.0e38f, m2 = -3.0e38f;
    int jm = 0;

    stage(0, 0);
    __syncthreads();                           // chunk 0 resident

    for (int cb = 0; cb < 9; ++cb) {
        int buf = cb & 1;
        if (cb + 1 < 9) stage((cb + 1) * 16, (cb + 1) & 1);   // overlap with compute
        if (t < nA) {
            float x[16];
#pragma unroll
            for (int r = 0; r < 16; ++r) x[r] = tile[buf][r][t];
            if (cb < 4) {
                // DFL softmax-expectation, exact reference op order
                float mx = x[0];
#pragma unroll
                for (int r = 1; r < 16; ++r) mx = fmaxf(mx, x[r]);
                float e[16], s = 0.f;
#pragma unroll
                for (int r = 0; r < 16; ++r) { e[r] = expf(x[r] - mx); s = s + e[r]; }
                float dd = 0.f;
#pragma unroll
                for (int r = 0; r < 16; ++r) { float pr = e[r] / s; dd = dd + pr * (float)r; }
                d[cb] = dd;
            } else {
                int cbase = (cb - 4) * 16;
#pragma unroll
                for (int r = 0; r < 16; ++r) {
                    int c = cbase + r;
                    float v = x[r];
                    if (v > m) { m2 = m; m = v; jm = c; }
                    else if (v > m2) { m2 = v; }
                }
            }
        }
        if (cb < 8) __syncthreads();           // drains vmcnt: next chunk resident
    }

    if (t >= nA) return;

    // ----- key (slow exact path rare: tie-gap < 1e-4 or saturated sigmoid) -----
    const float* pc = pb + (size_t)64 * A_TOT + a;
    float conf; int cls = jm;
    if ((m - m2) < 1e-4f || m > 7.0f) {
        float sb = -1.0f; int jb = 0;
        for (int c = 0; c < NCLS; ++c) {
            float s = sig32(pc[(size_t)c * A_TOT]);
            if (s > sb) { sb = s; jb = c; }
        }
        conf = sb; cls = jb;
    } else {
        conf = sig32(m);
    }
    float score = (conf > 0.25f) ? conf : -1.0f;
    u32 hi = key_hi_from_score(score);
    u32 lo = ((0x3FFFu - (u32)a) << 7) | (u32)cls;   // idx asc tie-break + cls
    key_raw[(size_t)b * A_TOT + a] = ((u64)hi << 32) | lo;

    // ----- box from d[0..3], exact reference op order -----
    int row, col; float stride;
    if (a < 6400)      { row = a / 80;          col = a % 80;          stride = 8.0f; }
    else if (a < 8000) { int aa = a - 6400; row = aa / 40; col = aa % 40; stride = 16.0f; }
    else               { int aa = a - 8000; row = aa / 20; col = aa % 20; stride = 32.0f; }
    float ax = (float)col + 0.5f;
    float ay = (float)row + 0.5f;
    float x1 = ax - d[0], y1 = ay - d[1];
    float x2 = ax + d[2], y2 = ay + d[3];
    float cx = (x1 + x2) / 2.0f, cy = (y1 + y2) / 2.0f;
    float w  = x2 - x1,          h  = y2 - y1;
    float4 db;
    db.x = cx * stride; db.y = cy * stride; db.z = w * stride; db.w = h * stride;
    dbox[(size_t)b * A_TOT + a] = db;
}

// ---------- 2a. bitonic sort of 1024-chunks (descending) ----------
__global__ __launch_bounds__(1024) void k_chunksort(const u64* __restrict__ key_raw,
                                                    u64* __restrict__ key_sorted) {
    __shared__ u64 s[KSLOT];
    int b = blockIdx.y, ch = blockIdx.x, t = threadIdx.x;
    int a = ch * KSLOT + t;
    s[t] = (a < A_TOT) ? key_raw[(size_t)b * A_TOT + a] : 0ull;
    __syncthreads();
    for (int k = 2; k <= KSLOT; k <<= 1) {
        for (int j = k >> 1; j > 0; j >>= 1) {
            int ixj = t ^ j;
            if (ixj > t) {
                u64 x = s[t], y = s[ixj];
                bool descBlock = ((t & k) == 0);
                bool sw = descBlock ? (x < y) : (x > y);
                if (sw) { s[t] = y; s[ixj] = x; }
            }
            __syncthreads();
        }
    }
    key_sorted[((size_t)b * NCHUNK + ch) * KSLOT + t] = s[t];
}

// ---------- 2b+3. select: merge-path tree top-1024 + inline prep (R9 form) ----------
__global__ __launch_bounds__(1024) void k_select(const u64* __restrict__ key_sorted,
                                                 u64* __restrict__ topk,
                                                 const float4* __restrict__ dbox,
                                                 float* __restrict__ tb,
                                                 float* __restrict__ ob,
                                                 float* __restrict__ area,
                                                 u32* __restrict__ validf) {
#pragma clang fp contract(off)
    __shared__ u64 L[5 * KSLOT];                 // 40 KB
    int b = blockIdx.x, t = threadIdx.x;
    const u64* KS = key_sorted + (size_t)b * NCHUNK * KSLOT;

    // Level 1: (0,1) (2,3) (4,5) (6,7) from global; chunk 8 copied
    u64 r0 = mp_rank(KS + 0 * KSLOT, KS + 1 * KSLOT, t);
    u64 r1 = mp_rank(KS + 2 * KSLOT, KS + 3 * KSLOT, t);
    u64 r2 = mp_rank(KS + 4 * KSLOT, KS + 5 * KSLOT, t);
    u64 r3 = mp_rank(KS + 6 * KSLOT, KS + 7 * KSLOT, t);
    u64 r4 = KS[8 * KSLOT + t];
    L[0 * KSLOT + t] = r0; L[1 * KSLOT + t] = r1;
    L[2 * KSLOT + t] = r2; L[3 * KSLOT + t] = r3;
    L[4 * KSLOT + t] = r4;
    __syncthreads();

    u64 m0 = mp_rank(L + 0 * KSLOT, L + 1 * KSLOT, t);
    u64 m1 = mp_rank(L + 2 * KSLOT, L + 3 * KSLOT, t);
    __syncthreads();
    L[0 * KSLOT + t] = m0; L[1 * KSLOT + t] = m1;
    __syncthreads();

    u64 s0 = mp_rank(L + 0 * KSLOT, L + 1 * KSLOT, t);
    __syncthreads();
    L[0 * KSLOT + t] = s0;
    __syncthreads();

    u64 key = mp_rank(L + 0 * KSLOT, L + 4 * KSLOT, t);
    size_t si = (size_t)b * KSLOT + t;
    topk[si] = key;

    // ----- inline prep (textually identical math) -----
    u32 hi = (u32)(key >> 32);
    u32 lo = (u32)key;
    bool valid = (t < TOPK_N) && (hi & 0x80000000u);
    if (!valid) {
        tb[si*4+0]=0.f; tb[si*4+1]=0.f; tb[si*4+2]=0.f; tb[si*4+3]=0.f;
        ob[si*4+0]=0.f; ob[si*4+1]=0.f; ob[si*4+2]=0.f; ob[si*4+3]=0.f;
        area[si] = 0.f; validf[si] = 0u;
        return;
    }
    int a   = 0x3FFF - (int)((lo >> 7) & 0x3FFFu);
    int cls = (int)(lo & 0x7Fu);

    float4 db = dbox[(size_t)b * A_TOT + a];
    float bx1 = db.x - db.z / 2.0f, by1 = db.y - db.w / 2.0f;
    float bx2 = db.x + db.z / 2.0f, by2 = db.y + db.w / 2.0f;
    tb[si*4+0] = bx1; tb[si*4+1] = by1; tb[si*4+2] = bx2; tb[si*4+3] = by2;

    float off = (float)cls * 7680.0f;
    float o0 = bx1 + off, o1 = by1 + off, o2 = bx2 + off, o3 = by2 + off;
    ob[si*4+0] = o0; ob[si*4+1] = o1; ob[si*4+2] = o2; ob[si*4+3] = o3;
    area[si] = (o2 - o0) * (o3 - o1);
    validf[si] = 1u;
}

// ---------- 4. suppression bitmask matrix -> TRANSPOSED masksT[w][i] ----------
// Same IoU math/values as before; store layout transposed so the scan can
// broadcast-read word w of any row (and coalesced 8B stores here).
__global__ __launch_bounds__(256) void k_matrix(const float* __restrict__ ob,
                                                const float* __restrict__ area,
                                                u64* __restrict__ masksT) {
#pragma clang fp contract(off)
    __shared__ float4 sob[KSLOT];
    __shared__ float  sar[KSLOT];
    int b = blockIdx.y, rblk = blockIdx.x, tid = threadIdx.x;
    const float4* gob = (const float4*)(ob + (size_t)b * KSLOT * 4);
    const float*  gar = area + (size_t)b * KSLOT;
    for (int i = tid; i < KSLOT; i += blockDim.x) { sob[i] = gob[i]; sar[i] = gar[i]; }
    __syncthreads();

    int lane = tid & 63;
    int wave = tid >> 6;               // 0..3
    int i = rblk * 64 + lane;
    float4 bi = sob[i];
    float Ai = sar[i];

#pragma unroll
    for (int wl = 0; wl < 4; ++wl) {
        int w = wave * 4 + wl;         // wave-uniform word index 0..15
        u64 mword = 0ull;
        if (w >= rblk) {               // whole word below diagonal -> all zero
            for (int bit = 0; bit < 64; ++bit) {
                int j = (w << 6) + bit;
                float4 bj = sob[j];    // broadcast (uniform addr across wave)
                float Aj = sar[j];     // broadcast
                float lt0 = fmaxf(bi.x, bj.x);
                float lt1 = fmaxf(bi.y, bj.y);
                float rb0 = fminf(bi.z, bj.z);
                float rb1 = fminf(bi.w, bj.w);
                float ww = fmaxf(rb0 - lt0, 0.0f);
                float hh = fmaxf(rb1 - lt1, 0.0f);
                float inter = ww * hh;
                float den = ((Ai + Aj) - inter) + 1e-7f;
                float iou = inter / den;
                if ((j > i) && (iou > 0.45f)) mword |= (1ull << bit);
            }
        }
        masksT[((size_t)b * 16 + w) * KSLOT + i] = mword;   // coalesced (i = lane)
    }
}

// ---------- 5. greedy scan: broadcast-chain (shfl-free) + fused finalize ----------
// Whole mask matrix staged into padded LDS MT[16][1025].
// MT[w][row] = suppression word w of GLOBAL row (0..1023) -- all reads below
// use rowi = cw*64 + bit (R12 bug was indexing with the bit alone).
// Critical chain per kept box = one broadcast ds_read + VALU; 1-ahead
// speculative candidate load hides most of that. Exact greedy semantics.
__global__ __launch_bounds__(1024) void k_scan(const u64* __restrict__ masksT,
                                               const u32* __restrict__ validf,
                                               const u64* __restrict__ topk,
                                               const float* __restrict__ tb,
                                               float* __restrict__ out) {
    __shared__ u64 MT[16][KSLOT + 1];
    __shared__ u64 validw[16];
    __shared__ u64 keepw[16];
    __shared__ int pref[16];
    int b = blockIdx.x, t = threadIdx.x;
    int lane = t & 63, wv = t >> 6;

    // stage full matrix (128KB) with coalesced loads; iter it covers word it
    const u64* src = masksT + (size_t)b * 16 * KSLOT;
    for (int it = 0; it < 16; ++it)
        MT[it][t] = src[it * KSLOT + t];
    // per-word valid ballots: wave wv owns word wv
    {
        u32 vf = validf[(size_t)b * KSLOT + wv * 64 + lane];
        u64 bal = __ballot(vf != 0u);
        if (lane == 0) validw[wv] = bal;
    }
    __syncthreads();

    if (wv == 0) {
        u64 rem = 0ull;                 // lanes 0-15 hold removed word 'lane'
        int kept = 0;
        for (int cw = 0; cw < 16; ++cw) {
            u64 kw = 0ull;
            u64 live = validw[cw] & ~__shfl(rem, cw);
            if (live) {
                int i1 = __ffsll(live) - 1;
                int ri1 = cw * 64 + i1;                    // GLOBAL row index
                u64 mA = MT[cw][ri1];                      // broadcast
                u64 rA = (lane < 16) ? MT[lane][ri1] : 0ull;
                for (;;) {
                    // commit i1 (lowest live bit is always kept)
                    kw |= (1ull << i1);
                    rem |= rA;
                    ++kept;
                    if (kept >= MAXDET) break;
                    u64 live2 = live & ~(1ull << i1);
                    if (!live2) break;
                    int i2 = __ffsll(live2) - 1;
                    int ri2 = cw * 64 + i2;
                    u64 mB = MT[cw][ri2];                  // speculative loads
                    u64 rB = (lane < 16) ? MT[lane][ri2] : 0ull;
                    live = live2 & ~mA;
                    if (!live) break;
                    int inext = __ffsll(live) - 1;
                    if (inext == i2) { i1 = i2; mA = mB; rA = rB; }
                    else {
                        i1 = inext;
                        int ri3 = cw * 64 + i1;
                        mA = MT[cw][ri3];
                        rA = (lane < 16) ? MT[lane][ri3] : 0ull;
                    }
                }
            }
            if (lane == 0) keepw[cw] = kw;
            if (kept >= MAXDET) {
                if (lane == 0)
                    for (int w2 = cw + 1; w2 < 16; ++w2) keepw[w2] = 0ull;
                break;
            }
        }
    }
    __syncthreads();

    // ---- fused finalize (R9 k_final math, 1024 threads) ----
    float* outb = out + (size_t)b * OUT_STRIDE;
    for (int z = t; z < OUT_STRIDE; z += 1024) outb[z] = 0.0f;
    if (t == 0) {
        int s = 0;
        for (int w = 0; w < 16; ++w) { pref[w] = s; s += __popcll(keepw[w]); }
    }
    __syncthreads();
    int w3 = t >> 6, bit3 = t & 63;
    if ((keepw[w3] >> bit3) & 1ull) {
        u64 below = (bit3 == 0) ? 0ull : (keepw[w3] & ((1ull << bit3) - 1ull));
        int rank = pref[w3] + __popcll(below);
        if (rank < MAXDET) {
            size_t si = (size_t)b * KSLOT + t;
            u64 key = topk[si];
            u32 hi = (u32)(key >> 32);
            u32 lo = (u32)key;
            float score = score_from_key_hi(hi);
            float clsf = (float)(lo & 0x7Fu);
            float* o = outb + rank * 6;
            o[0] = tb[si*4+0]; o[1] = tb[si*4+1];
            o[2] = tb[si*4+2]; o[3] = tb[si*4+3];
            o[4] = score; o[5] = clsf;
        }
    }
}

// ---------- launch ----------
extern "C" void kernel_launch(void* const* d_in, const int* in_sizes, int n_in,
                              void* d_out, int out_size, void* d_ws, size_t ws_size,
                              hipStream_t stream) {
    const float* preds = (const float*)d_in[0];
    float* out = (float*)d_out;
    int B = in_sizes[0] / (144 * A_TOT);

    char* ws = (char*)d_ws;
    size_t off = 0;
    u64* key_raw    = (u64*)(ws + off); off += (size_t)B * A_TOT * 8;
    u64* key_sorted = (u64*)(ws + off); off += (size_t)B * NCHUNK * KSLOT * 8;
    u64* topk       = (u64*)(ws + off); off += (size_t)B * KSLOT * 8;
    float4* dbox    = (float4*)(ws + off); off += (size_t)B * A_TOT * 16;
    float* tb       = (float*)(ws + off); off += (size_t)B * KSLOT * 4 * 4;
    float* obuf     = (float*)(ws + off); off += (size_t)B * KSLOT * 4 * 4;
    float* area     = (float*)(ws + off); off += (size_t)B * KSLOT * 4;
    u32* validf     = (u32*)(ws + off); off += (size_t)B * KSLOT * 4;
    u64* masksT     = (u64*)(ws + off); off += (size_t)B * 16 * KSLOT * 8;

    k_decode<<<dim3((A_TOT + 255) / 256, B), 256, 0, stream>>>(preds, key_raw, dbox);
    k_chunksort<<<dim3(NCHUNK, B), KSLOT, 0, stream>>>(key_raw, key_sorted);
    k_select<<<B, KSLOT, 0, stream>>>(key_sorted, topk, dbox, tb, obuf, area, validf);
    k_matrix<<<dim3(16, B), 256, 0, stream>>>(obuf, area, masksT);
    k_scan<<<B, KSLOT, 0, stream>>>(masksT, validf, topk, tb, out);
}

// Round 14
// 166.434 us; speedup vs baseline: 1.4529x; 1.0634x over previous
//
#include <hip/hip_runtime.h>
#include <cstdint>
#include <cstddef>

typedef unsigned long long u64;
typedef unsigned int u32;

#define A_TOT   8400
#define NCLS    80
#define KSLOT   1024
#define NCHUNK  9
#define TOPK_N  1000
#define MAXDET  300
#define OUT_STRIDE (MAXDET * 6)

#define GLOBAL_AS const __attribute__((address_space(1))) void*
#define LDS_AS __attribute__((address_space(3))) void*

// ---------- helpers ----------

// stepwise f32 sigmoid with correctly-rounded f32 exp (via f64):
// e = fl32(exp(-x)); s = 1/(1+e)   -- replicates np-f32 semantics
__device__ __forceinline__ float sig32(float x) {
#pragma clang fp contract(off)
    float e = (float)exp(-(double)x);
    float t = 1.0f + e;
    return 1.0f / t;
}

__device__ __forceinline__ u32 key_hi_from_score(float s) {
    u32 u = __float_as_uint(s);
    return (u & 0x80000000u) ? ~u : (u | 0x80000000u);
}
__device__ __forceinline__ float score_from_key_hi(u32 t) {
    u32 u = (t & 0x80000000u) ? (t ^ 0x80000000u) : ~t;
    return __uint_as_float(u);
}

// merge-path: element of rank t (0-based) in the descending merge of two
// descending length-1024 lists A, B (t < 1024). Values across A and B are
// distinct wherever it matters (unique anchor index in low bits; zero-pads
// only ever meet strictly-positive real keys), so strict '>' is exact.
__device__ __forceinline__ u64 mp_rank(const u64* A, const u64* B, int t) {
    int lo = 0, hi = t;
    while (lo < hi) {                     // find max i with (i==0 || A[i-1] > B[t-i])
        int mid = (lo + hi + 1) >> 1;
        if (A[mid - 1] > B[t - mid]) lo = mid; else hi = mid - 1;
    }
    int i = lo, j = t - lo;               // i,j <= t < 1024: A[i], B[j] always valid
    u64 av = A[i], bv = B[j];
    return av > bv ? av : bv;
}

// ---------- 1. fused decode: global_load_lds staging, 1 anchor/thread ----------
__global__ __launch_bounds__(256) void k_decode(const float* __restrict__ preds,
                                                u64* __restrict__ key_raw,
                                                float4* __restrict__ dbox) {
#pragma clang fp contract(off)
    __shared__ float tile[2][16][256];
    int b = blockIdx.y;
    int a0 = blockIdx.x * 256;
    int t = threadIdx.x;
    int a = a0 + t;
    int nA = A_TOT - a0; if (nA > 256) nA = 256;
    int p4max = nA >> 2;                       // valid float4s per channel row
    const float* pb = preds + (size_t)b * 144 * A_TOT;

    int l  = t & 63;                           // lane
    int wv = t >> 6;                           // wave 0..3
    int lc = (l < p4max) ? l : (p4max - 1);    // tail-safe clamped lane pos

    auto stage = [&](int ch0, int buf) {
#pragma unroll
        for (int k = 0; k < 4; ++k) {
            int r = 4 * k + wv;                // wave-uniform row
            const float* gsrc = pb + (size_t)(ch0 + r) * A_TOT + a0 + 4 * lc;
            __builtin_amdgcn_global_load_lds((GLOBAL_AS)gsrc,
                                             (LDS_AS)&tile[buf][r][0],
                                             16, 0, 0);
        }
    };

    float d[4] = {0.f, 0.f, 0.f, 0.f};
    float m = -3.0e38f, m2 = -3.0e38f;
    int jm = 0;

    stage(0, 0);
    __syncthreads();                           // chunk 0 resident

    for (int cb = 0; cb < 9; ++cb) {
        int buf = cb & 1;
        if (cb + 1 < 9) stage((cb + 1) * 16, (cb + 1) & 1);   // overlap with compute
        if (t < nA) {
            float x[16];
#pragma unroll
            for (int r = 0; r < 16; ++r) x[r] = tile[buf][r][t];
            if (cb < 4) {
                // DFL softmax-expectation, exact reference op order
                float mx = x[0];
#pragma unroll
                for (int r = 1; r < 16; ++r) mx = fmaxf(mx, x[r]);
                float e[16], s = 0.f;
#pragma unroll
                for (int r = 0; r < 16; ++r) { e[r] = expf(x[r] - mx); s = s + e[r]; }
                float dd = 0.f;
#pragma unroll
                for (int r = 0; r < 16; ++r) { float pr = e[r] / s; dd = dd + pr * (float)r; }
                d[cb] = dd;
            } else {
                int cbase = (cb - 4) * 16;
#pragma unroll
                for (int r = 0; r < 16; ++r) {
                    int c = cbase + r;
                    float v = x[r];
                    if (v > m) { m2 = m; m = v; jm = c; }
                    else if (v > m2) { m2 = v; }
                }
            }
        }
        if (cb < 8) __syncthreads();           // drains vmcnt: next chunk resident
    }

    if (t >= nA) return;

    // ----- key (slow exact path rare: tie-gap < 1e-4 or saturated sigmoid) -----
    const float* pc = pb + (size_t)64 * A_TOT + a;
    float conf; int cls = jm;
    if ((m - m2) < 1e-4f || m > 7.0f) {
        float sb = -1.0f; int jb = 0;
        for (int c = 0; c < NCLS; ++c) {
            float s = sig32(pc[(size_t)c * A_TOT]);
            if (s > sb) { sb = s; jb = c; }
        }
        conf = sb; cls = jb;
    } else {
        conf = sig32(m);
    }
    float score = (conf > 0.25f) ? conf : -1.0f;
    u32 hi = key_hi_from_score(score);
    u32 lo = ((0x3FFFu - (u32)a) << 7) | (u32)cls;   // idx asc tie-break + cls
    key_raw[(size_t)b * A_TOT + a] = ((u64)hi << 32) | lo;

    // ----- box from d[0..3], exact reference op order -----
    int row, col; float stride;
    if (a < 6400)      { row = a / 80;          col = a % 80;          stride = 8.0f; }
    else if (a < 8000) { int aa = a - 6400; row = aa / 40; col = aa % 40; stride = 16.0f; }
    else               { int aa = a - 8000; row = aa / 20; col = aa % 20; stride = 32.0f; }
    float ax = (float)col + 0.5f;
    float ay = (float)row + 0.5f;
    float x1 = ax - d[0], y1 = ay - d[1];
    float x2 = ax + d[2], y2 = ay + d[3];
    float cx = (x1 + x2) / 2.0f, cy = (y1 + y2) / 2.0f;
    float w  = x2 - x1,          h  = y2 - y1;
    float4 db;
    db.x = cx * stride; db.y = cy * stride; db.z = w * stride; db.w = h * stride;
    dbox[(size_t)b * A_TOT + a] = db;
}

// ---------- 2a. bitonic sort of 1024-chunks (descending) ----------
__global__ __launch_bounds__(1024) void k_chunksort(const u64* __restrict__ key_raw,
                                                    u64* __restrict__ key_sorted) {
    __shared__ u64 s[KSLOT];
    int b = blockIdx.y, ch = blockIdx.x, t = threadIdx.x;
    int a = ch * KSLOT + t;
    s[t] = (a < A_TOT) ? key_raw[(size_t)b * A_TOT + a] : 0ull;
    __syncthreads();
    for (int k = 2; k <= KSLOT; k <<= 1) {
        for (int j = k >> 1; j > 0; j >>= 1) {
            int ixj = t ^ j;
            if (ixj > t) {
                u64 x = s[t], y = s[ixj];
                bool descBlock = ((t & k) == 0);
                bool sw = descBlock ? (x < y) : (x > y);
                if (sw) { s[t] = y; s[ixj] = x; }
            }
            __syncthreads();
        }
    }
    key_sorted[((size_t)b * NCHUNK + ch) * KSLOT + t] = s[t];
}

// ---------- 2b+3. select: merge-path tree top-1024 + inline prep ----------
// 4 levels of pairwise rank-t merges; 9 barriers total (vs 88 bitonic phases).
__global__ __launch_bounds__(1024) void k_select(const u64* __restrict__ key_sorted,
                                                 u64* __restrict__ topk,
                                                 const float4* __restrict__ dbox,
                                                 float* __restrict__ tb,
                                                 float* __restrict__ ob,
                                                 float* __restrict__ area,
                                                 u32* __restrict__ validf) {
#pragma clang fp contract(off)
    __shared__ u64 L[5 * KSLOT];                 // 40 KB
    int b = blockIdx.x, t = threadIdx.x;
    const u64* KS = key_sorted + (size_t)b * NCHUNK * KSLOT;

    // Level 1: (0,1) (2,3) (4,5) (6,7) from global; chunk 8 copied
    u64 r0 = mp_rank(KS + 0 * KSLOT, KS + 1 * KSLOT, t);
    u64 r1 = mp_rank(KS + 2 * KSLOT, KS + 3 * KSLOT, t);
    u64 r2 = mp_rank(KS + 4 * KSLOT, KS + 5 * KSLOT, t);
    u64 r3 = mp_rank(KS + 6 * KSLOT, KS + 7 * KSLOT, t);
    u64 r4 = KS[8 * KSLOT + t];
    L[0 * KSLOT + t] = r0; L[1 * KSLOT + t] = r1;
    L[2 * KSLOT + t] = r2; L[3 * KSLOT + t] = r3;
    L[4 * KSLOT + t] = r4;
    __syncthreads();

    u64 m0 = mp_rank(L + 0 * KSLOT, L + 1 * KSLOT, t);
    u64 m1 = mp_rank(L + 2 * KSLOT, L + 3 * KSLOT, t);
    __syncthreads();
    L[0 * KSLOT + t] = m0; L[1 * KSLOT + t] = m1;
    __syncthreads();

    u64 s0 = mp_rank(L + 0 * KSLOT, L + 1 * KSLOT, t);
    __syncthreads();
    L[0 * KSLOT + t] = s0;
    __syncthreads();

    u64 key = mp_rank(L + 0 * KSLOT, L + 4 * KSLOT, t);
    size_t si = (size_t)b * KSLOT + t;
    topk[si] = key;

    // ----- inline prep (former k_prep, textually identical math) -----
    u32 hi = (u32)(key >> 32);
    u32 lo = (u32)key;
    bool valid = (t < TOPK_N) && (hi & 0x80000000u);
    if (!valid) {
        tb[si*4+0]=0.f; tb[si*4+1]=0.f; tb[si*4+2]=0.f; tb[si*4+3]=0.f;
        ob[si*4+0]=0.f; ob[si*4+1]=0.f; ob[si*4+2]=0.f; ob[si*4+3]=0.f;
        area[si] = 0.f; validf[si] = 0u;
        return;
    }
    int a   = 0x3FFF - (int)((lo >> 7) & 0x3FFFu);
    int cls = (int)(lo & 0x7Fu);

    float4 db = dbox[(size_t)b * A_TOT + a];
    float bx1 = db.x - db.z / 2.0f, by1 = db.y - db.w / 2.0f;
    float bx2 = db.x + db.z / 2.0f, by2 = db.y + db.w / 2.0f;
    tb[si*4+0] = bx1; tb[si*4+1] = by1; tb[si*4+2] = bx2; tb[si*4+3] = by2;

    float off = (float)cls * 7680.0f;
    float o0 = bx1 + off, o1 = by1 + off, o2 = bx2 + off, o3 = by2 + off;
    ob[si*4+0] = o0; ob[si*4+1] = o1; ob[si*4+2] = o2; ob[si*4+3] = o3;
    area[si] = (o2 - o0) * (o3 - o1);
    validf[si] = 1u;
}

// ---------- 4. suppression bitmask matrix: row i, bits j>i with iou>thr ----------
__global__ __launch_bounds__(256) void k_matrix(const float* __restrict__ ob,
                                                const float* __restrict__ area,
                                                u64* __restrict__ masks) {
#pragma clang fp contract(off)
    __shared__ float4 sob[KSLOT];
    __shared__ float  sar[KSLOT];
    int b = blockIdx.y, rblk = blockIdx.x, tid = threadIdx.x;
    const float4* gob = (const float4*)(ob + (size_t)b * KSLOT * 4);
    const float*  gar = area + (size_t)b * KSLOT;
    for (int i = tid; i < KSLOT; i += blockDim.x) { sob[i] = gob[i]; sar[i] = gar[i]; }
    __syncthreads();

    int lane = tid & 63;
    int wave = tid >> 6;               // 0..3
    int i = rblk * 64 + lane;
    float4 bi = sob[i];
    float Ai = sar[i];

#pragma unroll
    for (int wl = 0; wl < 4; ++wl) {
        int w = wave * 4 + wl;         // wave-uniform word index 0..15
        u64 mword = 0ull;
        if (w >= rblk) {               // whole word below diagonal -> all zero
            for (int bit = 0; bit < 64; ++bit) {
                int j = (w << 6) + bit;
                float4 bj = sob[j];    // broadcast (uniform addr across wave)
                float Aj = sar[j];     // broadcast
                float lt0 = fmaxf(bi.x, bj.x);
                float lt1 = fmaxf(bi.y, bj.y);
                float rb0 = fminf(bi.z, bj.z);
                float rb1 = fminf(bi.w, bj.w);
                float ww = fmaxf(rb0 - lt0, 0.0f);
                float hh = fmaxf(rb1 - lt1, 0.0f);
                float inter = ww * hh;
                float den = ((Ai + Aj) - inter) + 1e-7f;
                float iou = inter / den;
                if ((j > i) && (iou > 0.45f)) mword |= (1ull << bit);
            }
        }
        masks[((size_t)b * KSLOT + i) * 16 + w] = mword;
    }
}

// ---------- 5. greedy scan: live-mask skip, LDS-staged rows, early stop ----------
__global__ __launch_bounds__(64) void k_scan(const u64* __restrict__ masks,
                                             const u32* __restrict__ validf,
                                             u64* __restrict__ keep) {
    __shared__ u64 rows[KSLOT];          // 8KB: current word's 64 rows x 16 words
    int b = blockIdx.x, lane = threadIdx.x;
    const char* base = (const char*)(masks + (size_t)b * KSLOT * 16);

    // prefetch word 0's 8KB block into registers (coalesced dwordx4)
    float4 r0, r1, r2, r3, r4, r5, r6, r7;
    {
        const float4* src = (const float4*)base;
        r0 = src[0*64 + lane]; r1 = src[1*64 + lane];
        r2 = src[2*64 + lane]; r3 = src[3*64 + lane];
        r4 = src[4*64 + lane]; r5 = src[5*64 + lane];
        r6 = src[6*64 + lane]; r7 = src[7*64 + lane];
    }

    u64 kw = 0ull;       // lane l<16 owns keep word l
    u64 rem = 0ull;      // lane l<16 owns removed word l
    int kept = 0;

    for (int w = 0; w < 16; ++w) {
        // stage current word's rows into LDS
        {
            float4* dst = (float4*)rows;
            dst[0*64 + lane] = r0; dst[1*64 + lane] = r1;
            dst[2*64 + lane] = r2; dst[3*64 + lane] = r3;
            dst[4*64 + lane] = r4; dst[5*64 + lane] = r5;
            dst[6*64 + lane] = r6; dst[7*64 + lane] = r7;
        }
        u32 vf = validf[(size_t)b * KSLOT + w * 64 + lane];
        u64 valid_w = __ballot(vf != 0u);
        __syncthreads();
        // issue next word's loads (overlap with the serial scan below)
        if (w < 15) {
            const float4* src = (const float4*)(base + (size_t)(w + 1) * 8192);
            r0 = src[0*64 + lane]; r1 = src[1*64 + lane];
            r2 = src[2*64 + lane]; r3 = src[3*64 + lane];
            r4 = src[4*64 + lane]; r5 = src[5*64 + lane];
            r6 = src[6*64 + lane]; r7 = src[7*64 + lane];
        }

        u64 live = valid_w & ~__shfl(rem, w);
        while (live) {
            int i = __ffsll(live) - 1;           // lowest live slot: always kept
            if (lane == w) kw |= (1ull << i);
            u64 m = (lane < 16) ? rows[i * 16 + lane] : 0ull;
            rem |= m;
            ++kept;
            if (kept >= MAXDET) break;           // only first 300 kept are emitted
            live &= ~(__shfl(m, w) | (1ull << i));
        }
        if (kept >= MAXDET) break;
        __syncthreads();   // all lanes done reading rows before next overwrite
    }
    if (lane < 16) keep[(size_t)b * 16 + lane] = kw;
}

// ---------- 6. finalize: compact kept (ordered) into first 300 rows ----------
__global__ __launch_bounds__(1024) void k_final(const u64* __restrict__ keep,
                                                const u64* __restrict__ topk,
                                                const float* __restrict__ tb,
                                                float* __restrict__ out) {
    __shared__ u64 kw[16];
    __shared__ int pref[16];
    int b = blockIdx.x, t = threadIdx.x;
    float* ob_ = out + (size_t)b * OUT_STRIDE;
    for (int i = t; i < OUT_STRIDE; i += blockDim.x) ob_[i] = 0.0f;
    if (t < 16) kw[t] = keep[(size_t)b * 16 + t];
    __syncthreads();
    if (t == 0) {
        int s = 0;
        for (int w = 0; w < 16; ++w) { pref[w] = s; s += __popcll(kw[w]); }
    }
    __syncthreads();
    int w = t >> 6, bit = t & 63;
    bool kp = (kw[w] >> bit) & 1ull;
    if (kp) {
        u64 below = (bit == 0) ? 0ull : (kw[w] & ((1ull << bit) - 1ull));
        int rank = pref[w] + __popcll(below);
        if (rank < MAXDET) {
            size_t si = (size_t)b * KSLOT + t;
            u64 key = topk[si];
            u32 hi = (u32)(key >> 32);
            u32 lo = (u32)key;
            float score = score_from_key_hi(hi);
            float clsf = (float)(lo & 0x7Fu);
            float* o = ob_ + rank * 6;
            o[0] = tb[si*4+0]; o[1] = tb[si*4+1];
            o[2] = tb[si*4+2]; o[3] = tb[si*4+3];
            o[4] = score; o[5] = clsf;
        }
    }
}

// ---------- launch ----------
extern "C" void kernel_launch(void* const* d_in, const int* in_sizes, int n_in,
                              void* d_out, int out_size, void* d_ws, size_t ws_size,
                              hipStream_t stream) {
    const float* preds = (const float*)d_in[0];
    float* out = (float*)d_out;
    int B = in_sizes[0] / (144 * A_TOT);

    char* ws = (char*)d_ws;
    size_t off = 0;
    u64* key_raw    = (u64*)(ws + off); off += (size_t)B * A_TOT * 8;
    u64* key_sorted = (u64*)(ws + off); off += (size_t)B * NCHUNK * KSLOT * 8;
    u64* topk       = (u64*)(ws + off); off += (size_t)B * KSLOT * 8;
    float4* dbox    = (float4*)(ws + off); off += (size_t)B * A_TOT * 16;
    float* tb       = (float*)(ws + off); off += (size_t)B * KSLOT * 4 * 4;
    float* obuf     = (float*)(ws + off); off += (size_t)B * KSLOT * 4 * 4;
    float* area     = (float*)(ws + off); off += (size_t)B * KSLOT * 4;
    u32* validf     = (u32*)(ws + off); off += (size_t)B * KSLOT * 4;
    u64* masks      = (u64*)(ws + off); off += (size_t)B * KSLOT * 16 * 8;
    u64* keep       = (u64*)(ws + off); off += (size_t)B * 16 * 8;

    k_decode<<<dim3((A_TOT + 255) / 256, B), 256, 0, stream>>>(preds, key_raw, dbox);
    k_chunksort<<<dim3(NCHUNK, B), KSLOT, 0, stream>>>(key_raw, key_sorted);
    k_select<<<B, KSLOT, 0, stream>>>(key_sorted, topk, dbox, tb, obuf, area, validf);
    k_matrix<<<dim3(16, B), 256, 0, stream>>>(obuf, area, masks);
    k_scan<<<B, 64, 0, stream>>>(masks, validf, keep);
    k_final<<<B, 1024, 0, stream>>>(keep, topk, tb, out);
}